// Round 11
// baseline (262.997 us; speedup 1.0000x reference)
//
#include <hip/hip_runtime.h>
#include <math.h>

#define IN_DIM 128
#define HID    128
#define NN     100000
#define WPACK_BYTES (64 * 64 * 16)       // 64 frags x 64 lanes x 16B = 64 KB
#define WPACK_OFF   64
#define UBF_OFF     (WPACK_OFF + WPACK_BYTES + 192)   // 256-aligned
#define UBF_BYTES   (NN * HID * 2)                    // 25.6 MB
#define VBF_OFF     (UBF_OFF + UBF_BYTES)
#define VBF_BYTES   (NN * HID * 2)                    // 25.6 MB

typedef __attribute__((ext_vector_type(8))) __bf16 bf16x8;
typedef __attribute__((ext_vector_type(4))) float  f32x4;

__device__ __forceinline__ unsigned pk2bf(float a, float b) {
    union { __bf16 h[2]; unsigned u; } r;
    r.h[0] = (__bf16)a; r.h[1] = (__bf16)b;   // v_cvt_pk_bf16_f32
    return r.u;
}
__device__ __forceinline__ bf16x8 asbf(uint4 v) { return __builtin_bit_cast(bf16x8, v); }
__device__ __forceinline__ float bflo(unsigned w) { return __uint_as_float(w << 16); }
__device__ __forceinline__ float bfhi(unsigned w) { return __uint_as_float(w & 0xffff0000u); }

// dtype probe + W1 -> per-lane bf16 MFMA B-fragment pack
__global__ void prep(const float* __restrict__ W1,
                     const unsigned* __restrict__ ei,
                     uint4* __restrict__ wpack,
                     int* __restrict__ flag, int do_pack) {
    const int t = threadIdx.x;
    if (t < 64) {
        unsigned v = ei[2 * t + 1];
        unsigned long long b = __ballot(v != 0u);
        if (t == 0) flag[0] = (b == 0ull) ? 1 : 0;
    }
    if (!do_pack) return;
    const int lane = t & 63;
    #pragma unroll
    for (int fi = 0; fi < 16; ++fi) {
        const int frag = (t >> 6) + fi * 4;
        const int kc = frag >> 3, jsg = frag & 7;
        const int k0 = kc * 32 + (lane >> 4) * 8;
        const int j  = jsg * 16 + (lane & 15);
        unsigned wv[4];
        #pragma unroll
        for (int p = 0; p < 4; ++p)
            wv[p] = pk2bf(W1[(k0 + 2 * p) * HID + j], W1[(k0 + 2 * p + 1) * HID + j]);
        wpack[frag * 64 + lane] = make_uint4(wv[0], wv[1], wv[2], wv[3]);
    }
}

// U = z*W1[0:128,:], V = z*W1[128:256,:] per node, bf16, PERMUTED row layout
// (row byte l4*16 + jsg*2 holds col j = jsg*16 + l4).
// R11 design: NO LDS, NO barriers, one independent 16-node tile per wave.
// W1 B-frags (64 KB) read straight from L2; occupancy capped only by VGPR.
__global__ __launch_bounds__(256, 4)
void uv_gemm(const float* __restrict__ z,
             const uint4* __restrict__ wpack,
             char* __restrict__ ubf, char* __restrict__ vbf,
             int nwt)
{
    const int t = threadIdx.x, lane = t & 63, w = t >> 6;
    const int l4 = lane & 15, q = lane >> 4;

    for (int wt = blockIdx.x * 4 + w; wt < nwt; wt += gridDim.x * 4) {
        const int node0 = wt * 16;
        const int arow  = min(node0 + l4, NN - 1);
        const float* zr = z + (long long)arow * IN_DIM + q * 8;

        f32x4 au[8] = {}, av[8] = {};
        #pragma unroll
        for (int kc = 0; kc < 4; ++kc) {
            const float4 f0 = *reinterpret_cast<const float4*>(zr + kc * 32);
            const float4 f1 = *reinterpret_cast<const float4*>(zr + kc * 32 + 4);
            const bf16x8 a = asbf(make_uint4(pk2bf(f0.x, f0.y), pk2bf(f0.z, f0.w),
                                             pk2bf(f1.x, f1.y), pk2bf(f1.z, f1.w)));
            #pragma unroll
            for (int jsg = 0; jsg < 8; ++jsg) {
                au[jsg] = __builtin_amdgcn_mfma_f32_16x16x32_bf16(
                    a, asbf(wpack[(kc * 8 + jsg) * 64 + lane]), au[jsg], 0, 0, 0);
                av[jsg] = __builtin_amdgcn_mfma_f32_16x16x32_bf16(
                    a, asbf(wpack[((kc + 4) * 8 + jsg) * 64 + lane]), av[jsg], 0, 0, 0);
            }
        }

        // store: D row = node0 + q*4 + reg; lane packs its 8 jsg values into
        // one uint4 -> 16 lanes cover the full 256B row; 4 rows = 1KB/instr.
        #pragma unroll
        for (int reg = 0; reg < 4; ++reg) {
            const int n = node0 + q * 4 + reg;
            if (n < NN) {
                const long long nb = (long long)n * 256 + l4 * 16;
                *reinterpret_cast<uint4*>(ubf + nb) =
                    make_uint4(pk2bf(au[0][reg], au[1][reg]), pk2bf(au[2][reg], au[3][reg]),
                               pk2bf(au[4][reg], au[5][reg]), pk2bf(au[6][reg], au[7][reg]));
                *reinterpret_cast<uint4*>(vbf + nb) =
                    make_uint4(pk2bf(av[0][reg], av[1][reg]), pk2bf(av[2][reg], av[3][reg]),
                               pk2bf(av[4][reg], av[5][reg]), pk2bf(av[6][reg], av[7][reg]));
            }
        }
    }
}

// Edge phase: pure streaming gather over permuted U/V rows.
// 16 lanes per edge; lane g reads 16B = cols {jsg*16+g : jsg=0..7}.
__global__ __launch_bounds__(256)
void lp_edge(const char* __restrict__ ubf, const char* __restrict__ vbf,
             const int* __restrict__ ei32,
             const float* __restrict__ b1, const float* __restrict__ W2,
             const float* __restrict__ b2, float* __restrict__ out,
             const int* __restrict__ flag, int E)
{
    const int t = threadIdx.x;
    const int g = t & 15;
    const int use64 = flag[0];
    float b1p[8], w2p[8];
    #pragma unroll
    for (int jsg = 0; jsg < 8; ++jsg) {
        b1p[jsg] = b1[jsg * 16 + g];
        w2p[jsg] = W2[jsg * 16 + g];
    }
    const float b2v = b2[0];

    for (int e = blockIdx.x * 16 + (t >> 4); e < E; e += gridDim.x * 16) {
        int s = ei32[(long long)e << use64];
        int d = ei32[(long long)(E + e) << use64];
        s = min(max(s, 0), NN - 1);
        d = min(max(d, 0), NN - 1);
        const uint4 uu = *reinterpret_cast<const uint4*>(ubf + (long long)s * 256 + g * 16);
        const uint4 vv = *reinterpret_cast<const uint4*>(vbf + (long long)d * 256 + g * 16);

        float acc;
        acc  = fmaxf(bflo(uu.x) + bflo(vv.x) + b1p[0], 0.f) * w2p[0];
        acc += fmaxf(bfhi(uu.x) + bfhi(vv.x) + b1p[1], 0.f) * w2p[1];
        acc += fmaxf(bflo(uu.y) + bflo(vv.y) + b1p[2], 0.f) * w2p[2];
        acc += fmaxf(bfhi(uu.y) + bfhi(vv.y) + b1p[3], 0.f) * w2p[3];
        acc += fmaxf(bflo(uu.z) + bflo(vv.z) + b1p[4], 0.f) * w2p[4];
        acc += fmaxf(bfhi(uu.z) + bfhi(vv.z) + b1p[5], 0.f) * w2p[5];
        acc += fmaxf(bflo(uu.w) + bflo(vv.w) + b1p[6], 0.f) * w2p[6];
        acc += fmaxf(bfhi(uu.w) + bfhi(vv.w) + b1p[7], 0.f) * w2p[7];

        acc += __shfl_xor(acc, 1);
        acc += __shfl_xor(acc, 2);
        acc += __shfl_xor(acc, 4);
        acc += __shfl_xor(acc, 8);
        if (g == 0) out[e] = 1.f / (1.f + expf(-(acc + b2v)));
    }
}

// ---------------- fallback (R5-proven fp32-gather kernel) ----------------
__global__ __launch_bounds__(256, 3)
void lp_main(const float* __restrict__ z,
             const int* __restrict__ ei32,
             const float* __restrict__ W1,
             const float* __restrict__ b1,
             const float* __restrict__ W2,
             const float* __restrict__ b2,
             float* __restrict__ out,
             const int* __restrict__ flag,
             const uint4* __restrict__ wpack,
             int use_ws, int E, int ntiles)
{
    __shared__ uint4 ldsA_[64 * 512 / 16];
    __shared__ float part[4][64];
    char* ldsc = (char*)ldsA_;

    const int t = threadIdx.x, lane = t & 63, w = t >> 6;
    const int use64 = flag[0];

    uint4 Bf[8][2];
    if (use_ws) {
        #pragma unroll
        for (int kc = 0; kc < 8; ++kc)
            #pragma unroll
            for (int js = 0; js < 2; ++js)
                Bf[kc][js] = wpack[(kc * 8 + (w * 2 + js)) * 64 + lane];
    } else {
        #pragma unroll
        for (int kc = 0; kc < 8; ++kc)
            #pragma unroll
            for (int js = 0; js < 2; ++js) {
                const int k0 = kc * 32 + (lane >> 4) * 8;
                const int j  = (w * 2 + js) * 16 + (lane & 15);
                unsigned wv[4];
                #pragma unroll
                for (int p = 0; p < 4; ++p)
                    wv[p] = pk2bf(W1[(k0 + 2 * p) * HID + j],
                                  W1[(k0 + 2 * p + 1) * HID + j]);
                Bf[kc][js] = make_uint4(wv[0], wv[1], wv[2], wv[3]);
            }
    }

    const int e_r = lane & 15, q = lane >> 4, m16 = q * 16;
    const float b1v0 = b1[w * 32 + e_r], b1v1 = b1[w * 32 + 16 + e_r];
    const float w2v0 = W2[w * 32 + e_r], w2v1 = W2[w * 32 + 16 + e_r];
    const float b2v  = b2[0];

    for (int tile = blockIdx.x; tile < ntiles; tile += gridDim.x) {
        const int e0 = tile * 64;
        #pragma unroll 8
        for (int i = 0; i < 16; ++i) {
            const int el = i * 4 + w;
            int e = e0 + el; if (e > E - 1) e = E - 1;
            const int word = (lane < 32) ? e : (E + e);
            int node = ei32[(long long)word << use64];
            node = min(max(node, 0), NN - 1);
            const float4 v = *reinterpret_cast<const float4*>(
                &z[node * IN_DIM + (lane & 31) * 4]);
            const int byte = el * 512 + ((lane * 8) ^ ((el & 7) << 4));
            *reinterpret_cast<uint2*>(ldsc + byte) =
                make_uint2(pk2bf(v.x, v.y), pk2bf(v.z, v.w));
        }
        __syncthreads();

        f32x4 acc[4][2] = {};
        #pragma unroll
        for (int kc = 0; kc < 8; ++kc) {
            #pragma unroll
            for (int es = 0; es < 4; ++es) {
                const int row  = es * 16 + e_r;
                const int byte = row * 512 + ((kc * 64 + m16) ^ ((row & 7) << 4));
                const bf16x8 a = *reinterpret_cast<const bf16x8*>(ldsc + byte);
                acc[es][0] = __builtin_amdgcn_mfma_f32_16x16x32_bf16(
                    a, asbf(Bf[kc][0]), acc[es][0], 0, 0, 0);
                acc[es][1] = __builtin_amdgcn_mfma_f32_16x16x32_bf16(
                    a, asbf(Bf[kc][1]), acc[es][1], 0, 0, 0);
            }
        }

        float v16[16];
        #pragma unroll
        for (int es = 0; es < 4; ++es)
            #pragma unroll
            for (int reg = 0; reg < 4; ++reg)
                v16[es * 4 + reg] = fmaxf(acc[es][0][reg] + b1v0, 0.f) * w2v0
                                  + fmaxf(acc[es][1][reg] + b1v1, 0.f) * w2v1;
        #pragma unroll
        for (int rnd = 0; rnd < 4; ++rnd) {
            const int o = 1 << rnd, hl = 8 >> rnd;
            #pragma unroll
            for (int i = 0; i < hl; ++i) {
                const float a = v16[i], b = v16[i + hl];
                const float s = (lane & o) ? a : b;
                const float r = __shfl_xor(s, o);
                v16[i] = ((lane & o) ? b : a) + r;
            }
        }
        {
            const int lx  = lane & 15;
            const int idx = ((lx & 1) << 3) | ((lx & 2) << 1) | ((lx & 4) >> 1) | ((lx & 8) >> 3);
            const int edge = (idx >> 2) * 16 + q * 4 + (idx & 3);
            part[w][edge] = v16[0];
        }
        __syncthreads();

        if (t < 64) {
            const int e = e0 + t;
            if (e < E) {
                const float s = part[0][t] + part[1][t] + part[2][t] + part[3][t] + b2v;
                out[e] = 1.f / (1.f + expf(-s));
            }
        }
    }
}

extern "C" void kernel_launch(void* const* d_in, const int* in_sizes, int n_in,
                              void* d_out, int out_size, void* d_ws, size_t ws_size,
                              hipStream_t stream) {
    const float* z  = (const float*)d_in[0];
    const void*  ei = d_in[1];
    const float* W1 = (const float*)d_in[2];
    const float* b1 = (const float*)d_in[3];
    const float* W2 = (const float*)d_in[4];
    const float* b2 = (const float*)d_in[5];
    float* out = (float*)d_out;
    int*   flag  = (int*)d_ws;
    uint4* wpack = (uint4*)((char*)d_ws + WPACK_OFF);
    char*  ubf   = (char*)d_ws + UBF_OFF;
    char*  vbf   = (char*)d_ws + VBF_OFF;

    const int E = in_sizes[1] / 2;
    const int use_ws = (ws_size >= (size_t)(WPACK_OFF + WPACK_BYTES)) ? 1 : 0;
    const int use_uv = (ws_size >= (size_t)(VBF_OFF + VBF_BYTES)) ? 1 : 0;

    hipLaunchKernelGGL(prep, dim3(1), dim3(256), 0, stream,
                       W1, (const unsigned*)ei, wpack, flag, use_ws);

    if (use_uv) {
        const int nwt = (NN + 15) / 16;                    // 6250 wave-tiles
        const int g1  = (nwt + 3) / 4;                     // 1563: 1 tile per wave
        hipLaunchKernelGGL(uv_gemm, dim3(g1), dim3(256), 0, stream,
                           z, wpack, ubf, vbf, nwt);
        hipLaunchKernelGGL(lp_edge, dim3(2048), dim3(256), 0, stream,
                           ubf, vbf, (const int*)ei, b1, W2, b2, out, flag, E);
    } else {
        const int ntiles = (E + 63) / 64;
        const int grid = (ntiles < 768) ? ntiles : 768;
        hipLaunchKernelGGL(lp_main, dim3(grid), dim3(256), 0, stream,
                           z, (const int*)ei, W1, b1, W2, b2, out, flag, wpack,
                           use_ws, E, ntiles);
    }
}

// Round 12
// 117.441 us; speedup vs baseline: 2.2394x; 2.2394x over previous
//
#include <hip/hip_runtime.h>
#include <math.h>

#define IN_DIM 128
#define HID    128
#define NN     100000
#define WPACK_BYTES (64 * 64 * 16)       // 64 frags x 64 lanes x 16B = 64 KB
#define WPACK_OFF   64
#define UBF_OFF     (WPACK_OFF + WPACK_BYTES + 192)   // 256-aligned
#define UBF_BYTES   (NN * HID * 2)                    // 25.6 MB
#define VBF_OFF     (UBF_OFF + UBF_BYTES)
#define VBF_BYTES   (NN * HID * 2)                    // 25.6 MB

typedef __attribute__((ext_vector_type(8))) __bf16 bf16x8;
typedef __attribute__((ext_vector_type(4))) float  f32x4;

__device__ __forceinline__ unsigned pk2bf(float a, float b) {
    union { __bf16 h[2]; unsigned u; } r;
    r.h[0] = (__bf16)a; r.h[1] = (__bf16)b;   // v_cvt_pk_bf16_f32
    return r.u;
}
__device__ __forceinline__ bf16x8 asbf(uint4 v) { return __builtin_bit_cast(bf16x8, v); }
__device__ __forceinline__ float bflo(unsigned w) { return __uint_as_float(w << 16); }
__device__ __forceinline__ float bfhi(unsigned w) { return __uint_as_float(w & 0xffff0000u); }

// dtype probe + W1 -> per-lane bf16 MFMA B-fragment pack
__global__ void prep(const float* __restrict__ W1,
                     const unsigned* __restrict__ ei,
                     uint4* __restrict__ wpack,
                     int* __restrict__ flag, int do_pack) {
    const int t = threadIdx.x;
    if (t < 64) {
        unsigned v = ei[2 * t + 1];
        unsigned long long b = __ballot(v != 0u);
        if (t == 0) flag[0] = (b == 0ull) ? 1 : 0;
    }
    if (!do_pack) return;
    const int lane = t & 63;
    #pragma unroll
    for (int fi = 0; fi < 16; ++fi) {
        const int frag = (t >> 6) + fi * 4;
        const int kc = frag >> 3, jsg = frag & 7;
        const int k0 = kc * 32 + (lane >> 4) * 8;
        const int j  = jsg * 16 + (lane & 15);
        unsigned wv[4];
        #pragma unroll
        for (int p = 0; p < 4; ++p)
            wv[p] = pk2bf(W1[(k0 + 2 * p) * HID + j], W1[(k0 + 2 * p + 1) * HID + j]);
        wpack[frag * 64 + lane] = make_uint4(wv[0], wv[1], wv[2], wv[3]);
    }
}

// uv_gemm v4: quadrant-per-wave, W register-resident, zero LDS, zero barriers.
// Wave w of each block owns {U if w<2 else V} x {j-half w&1}: 16KB of W1 in
// 64 VGPRs, loaded ONCE per persistent block. All 4 waves read the same 16
// z-rows (L1 hits). Store: lane writes uint2 -> 16 lanes = 128B contiguous;
// every 128B line has exactly one writer instruction (kills R11's 8.5x WRITE).
// UV row layout: byte jh*128 + l4*8 + jsg*2 holds col j = jh*64 + jsg*16 + l4.
__global__ __launch_bounds__(256)
void uv_gemm(const float* __restrict__ z,
             const uint4* __restrict__ wpack,
             char* __restrict__ ubf, char* __restrict__ vbf,
             int nwt)
{
    const int t = threadIdx.x, lane = t & 63, w = t >> 6;
    const int l4 = lane & 15, q = lane >> 4;
    const int jh = w & 1;
    char* obuf = (w >= 2) ? vbf : ubf;

    // this wave's W quadrant: rows (w>>1)*128 + 0..127, cols jh*64 + 0..63
    uint4 Bf[4][4];
    #pragma unroll
    for (int kc = 0; kc < 4; ++kc)
        #pragma unroll
        for (int jsg = 0; jsg < 4; ++jsg)
            Bf[kc][jsg] = wpack[((((w >> 1) * 4 + kc) * 8) + jh * 4 + jsg) * 64 + lane];

    for (int wt = blockIdx.x; wt < nwt; wt += gridDim.x) {
        // hard in-loop liveness for Bf (R5: pre-loop pin rematerializes;
        // demand here ~115 VGPR < 128, so no R6-style spill)
        #pragma unroll
        for (int kc = 0; kc < 4; ++kc)
            #pragma unroll
            for (int jsg = 0; jsg < 4; ++jsg)
                asm volatile("" : "+v"(Bf[kc][jsg].x), "+v"(Bf[kc][jsg].y),
                                  "+v"(Bf[kc][jsg].z), "+v"(Bf[kc][jsg].w));

        const int node0 = wt * 16;                       // NN % 16 == 0
        const float* zr = z + (long long)(node0 + l4) * IN_DIM + q * 8;

        f32x4 acc[4] = {};
        #pragma unroll
        for (int kc = 0; kc < 4; ++kc) {
            const float4 f0 = *reinterpret_cast<const float4*>(zr + kc * 32);
            const float4 f1 = *reinterpret_cast<const float4*>(zr + kc * 32 + 4);
            const bf16x8 a = asbf(make_uint4(pk2bf(f0.x, f0.y), pk2bf(f0.z, f0.w),
                                             pk2bf(f1.x, f1.y), pk2bf(f1.z, f1.w)));
            #pragma unroll
            for (int jsg = 0; jsg < 4; ++jsg)
                acc[jsg] = __builtin_amdgcn_mfma_f32_16x16x32_bf16(
                    a, asbf(Bf[kc][jsg]), acc[jsg], 0, 0, 0);
        }

        #pragma unroll
        for (int reg = 0; reg < 4; ++reg) {
            const int n = node0 + q * 4 + reg;           // always < NN
            *reinterpret_cast<uint2*>(obuf + (long long)n * 256 + jh * 128 + l4 * 8) =
                make_uint2(pk2bf(acc[0][reg], acc[1][reg]),
                           pk2bf(acc[2][reg], acc[3][reg]));
        }
    }
}

// Edge phase: streaming gather over permuted U/V rows.
// Lane g reads 16B at byte g*16: jh = g>>3, covers l4 = 2*(g&7) and +1,
// each with jsg 0..3 -> cols jh*64 + jsg*16 + l4.
__global__ __launch_bounds__(256)
void lp_edge(const char* __restrict__ ubf, const char* __restrict__ vbf,
             const int* __restrict__ ei32,
             const float* __restrict__ b1, const float* __restrict__ W2,
             const float* __restrict__ b2, float* __restrict__ out,
             const int* __restrict__ flag, int E)
{
    const int t = threadIdx.x;
    const int g = t & 15;
    const int use64 = flag[0];
    const int jh = g >> 3, la = 2 * (g & 7), lb = la + 1;
    float b1p[8], w2p[8];
    #pragma unroll
    for (int jsg = 0; jsg < 4; ++jsg) {
        b1p[jsg]     = b1[jh * 64 + jsg * 16 + la];
        b1p[jsg + 4] = b1[jh * 64 + jsg * 16 + lb];
        w2p[jsg]     = W2[jh * 64 + jsg * 16 + la];
        w2p[jsg + 4] = W2[jh * 64 + jsg * 16 + lb];
    }
    const float b2v = b2[0];

    for (int e = blockIdx.x * 16 + (t >> 4); e < E; e += gridDim.x * 16) {
        int s = ei32[(long long)e << use64];
        int d = ei32[(long long)(E + e) << use64];
        s = min(max(s, 0), NN - 1);
        d = min(max(d, 0), NN - 1);
        const uint4 uu = *reinterpret_cast<const uint4*>(ubf + (long long)s * 256 + g * 16);
        const uint4 vv = *reinterpret_cast<const uint4*>(vbf + (long long)d * 256 + g * 16);

        float acc;
        acc  = fmaxf(bflo(uu.x) + bflo(vv.x) + b1p[0], 0.f) * w2p[0];
        acc += fmaxf(bfhi(uu.x) + bfhi(vv.x) + b1p[1], 0.f) * w2p[1];
        acc += fmaxf(bflo(uu.y) + bflo(vv.y) + b1p[2], 0.f) * w2p[2];
        acc += fmaxf(bfhi(uu.y) + bfhi(vv.y) + b1p[3], 0.f) * w2p[3];
        acc += fmaxf(bflo(uu.z) + bflo(vv.z) + b1p[4], 0.f) * w2p[4];
        acc += fmaxf(bfhi(uu.z) + bfhi(vv.z) + b1p[5], 0.f) * w2p[5];
        acc += fmaxf(bflo(uu.w) + bflo(vv.w) + b1p[6], 0.f) * w2p[6];
        acc += fmaxf(bfhi(uu.w) + bfhi(vv.w) + b1p[7], 0.f) * w2p[7];

        acc += __shfl_xor(acc, 1);
        acc += __shfl_xor(acc, 2);
        acc += __shfl_xor(acc, 4);
        acc += __shfl_xor(acc, 8);
        if (g == 0) out[e] = 1.f / (1.f + expf(-(acc + b2v)));
    }
}

// ---------------- fallback (R5-proven fp32-gather kernel) ----------------
__global__ __launch_bounds__(256, 3)
void lp_main(const float* __restrict__ z,
             const int* __restrict__ ei32,
             const float* __restrict__ W1,
             const float* __restrict__ b1,
             const float* __restrict__ W2,
             const float* __restrict__ b2,
             float* __restrict__ out,
             const int* __restrict__ flag,
             const uint4* __restrict__ wpack,
             int use_ws, int E, int ntiles)
{
    __shared__ uint4 ldsA_[64 * 512 / 16];
    __shared__ float part[4][64];
    char* ldsc = (char*)ldsA_;

    const int t = threadIdx.x, lane = t & 63, w = t >> 6;
    const int use64 = flag[0];

    uint4 Bf[8][2];
    if (use_ws) {
        #pragma unroll
        for (int kc = 0; kc < 8; ++kc)
            #pragma unroll
            for (int js = 0; js < 2; ++js)
                Bf[kc][js] = wpack[(kc * 8 + (w * 2 + js)) * 64 + lane];
    } else {
        #pragma unroll
        for (int kc = 0; kc < 8; ++kc)
            #pragma unroll
            for (int js = 0; js < 2; ++js) {
                const int k0 = kc * 32 + (lane >> 4) * 8;
                const int j  = (w * 2 + js) * 16 + (lane & 15);
                unsigned wv[4];
                #pragma unroll
                for (int p = 0; p < 4; ++p)
                    wv[p] = pk2bf(W1[(k0 + 2 * p) * HID + j],
                                  W1[(k0 + 2 * p + 1) * HID + j]);
                Bf[kc][js] = make_uint4(wv[0], wv[1], wv[2], wv[3]);
            }
    }

    const int e_r = lane & 15, q = lane >> 4, m16 = q * 16;
    const float b1v0 = b1[w * 32 + e_r], b1v1 = b1[w * 32 + 16 + e_r];
    const float w2v0 = W2[w * 32 + e_r], w2v1 = W2[w * 32 + 16 + e_r];
    const float b2v  = b2[0];

    for (int tile = blockIdx.x; tile < ntiles; tile += gridDim.x) {
        const int e0 = tile * 64;
        #pragma unroll 8
        for (int i = 0; i < 16; ++i) {
            const int el = i * 4 + w;
            int e = e0 + el; if (e > E - 1) e = E - 1;
            const int word = (lane < 32) ? e : (E + e);
            int node = ei32[(long long)word << use64];
            node = min(max(node, 0), NN - 1);
            const float4 v = *reinterpret_cast<const float4*>(
                &z[node * IN_DIM + (lane & 31) * 4]);
            const int byte = el * 512 + ((lane * 8) ^ ((el & 7) << 4));
            *reinterpret_cast<uint2*>(ldsc + byte) =
                make_uint2(pk2bf(v.x, v.y), pk2bf(v.z, v.w));
        }
        __syncthreads();

        f32x4 acc[4][2] = {};
        #pragma unroll
        for (int kc = 0; kc < 8; ++kc) {
            #pragma unroll
            for (int es = 0; es < 4; ++es) {
                const int row  = es * 16 + e_r;
                const int byte = row * 512 + ((kc * 64 + m16) ^ ((row & 7) << 4));
                const bf16x8 a = *reinterpret_cast<const bf16x8*>(ldsc + byte);
                acc[es][0] = __builtin_amdgcn_mfma_f32_16x16x32_bf16(
                    a, asbf(Bf[kc][0]), acc[es][0], 0, 0, 0);
                acc[es][1] = __builtin_amdgcn_mfma_f32_16x16x32_bf16(
                    a, asbf(Bf[kc][1]), acc[es][1], 0, 0, 0);
            }
        }

        float v16[16];
        #pragma unroll
        for (int es = 0; es < 4; ++es)
            #pragma unroll
            for (int reg = 0; reg < 4; ++reg)
                v16[es * 4 + reg] = fmaxf(acc[es][0][reg] + b1v0, 0.f) * w2v0
                                  + fmaxf(acc[es][1][reg] + b1v1, 0.f) * w2v1;
        #pragma unroll
        for (int rnd = 0; rnd < 4; ++rnd) {
            const int o = 1 << rnd, hl = 8 >> rnd;
            #pragma unroll
            for (int i = 0; i < hl; ++i) {
                const float a = v16[i], b = v16[i + hl];
                const float s = (lane & o) ? a : b;
                const float r = __shfl_xor(s, o);
                v16[i] = ((lane & o) ? b : a) + r;
            }
        }
        {
            const int lx  = lane & 15;
            const int idx = ((lx & 1) << 3) | ((lx & 2) << 1) | ((lx & 4) >> 1) | ((lx & 8) >> 3);
            const int edge = (idx >> 2) * 16 + q * 4 + (idx & 3);
            part[w][edge] = v16[0];
        }
        __syncthreads();

        if (t < 64) {
            const int e = e0 + t;
            if (e < E) {
                const float s = part[0][t] + part[1][t] + part[2][t] + part[3][t] + b2v;
                out[e] = 1.f / (1.f + expf(-s));
            }
        }
    }
}

extern "C" void kernel_launch(void* const* d_in, const int* in_sizes, int n_in,
                              void* d_out, int out_size, void* d_ws, size_t ws_size,
                              hipStream_t stream) {
    const float* z  = (const float*)d_in[0];
    const void*  ei = d_in[1];
    const float* W1 = (const float*)d_in[2];
    const float* b1 = (const float*)d_in[3];
    const float* W2 = (const float*)d_in[4];
    const float* b2 = (const float*)d_in[5];
    float* out = (float*)d_out;
    int*   flag  = (int*)d_ws;
    uint4* wpack = (uint4*)((char*)d_ws + WPACK_OFF);
    char*  ubf   = (char*)d_ws + UBF_OFF;
    char*  vbf   = (char*)d_ws + VBF_OFF;

    const int E = in_sizes[1] / 2;
    const int use_ws = (ws_size >= (size_t)(WPACK_OFF + WPACK_BYTES)) ? 1 : 0;
    const int use_uv = (ws_size >= (size_t)(VBF_OFF + VBF_BYTES)) ? 1 : 0;

    hipLaunchKernelGGL(prep, dim3(1), dim3(256), 0, stream,
                       W1, (const unsigned*)ei, wpack, flag, use_ws);

    if (use_uv) {
        const int nwt = NN / 16;                           // 6250, exact
        hipLaunchKernelGGL(uv_gemm, dim3(1024), dim3(256), 0, stream,
                           z, wpack, ubf, vbf, nwt);
        hipLaunchKernelGGL(lp_edge, dim3(2048), dim3(256), 0, stream,
                           ubf, vbf, (const int*)ei, b1, W2, b2, out, flag, E);
    } else {
        const int ntiles = (E + 63) / 64;
        const int grid = (ntiles < 768) ? ntiles : 768;
        hipLaunchKernelGGL(lp_main, dim3(grid), dim3(256), 0, stream,
                           z, (const int*)ei, W1, b1, W2, b2, out, flag, wpack,
                           use_ws, E, ntiles);
    }
}

// Round 13
// 116.298 us; speedup vs baseline: 2.2614x; 1.0098x over previous
//
#include <hip/hip_runtime.h>
#include <hip/hip_fp16.h>
#include <math.h>

#define IN_DIM 128
#define HID    128
#define NN     100000
#define WPACK_BYTES (64 * 64 * 16)       // 64 frags x 64 lanes x 16B = 64 KB
#define WPACK_OFF   64
#define UBF_OFF     (WPACK_OFF + WPACK_BYTES + 192)   // 256-aligned
#define UBF_BYTES   (NN * HID * 2)                    // 25.6 MB
#define VBF_OFF     (UBF_OFF + UBF_BYTES)
#define VBF_BYTES   (NN * HID * 2)                    // 25.6 MB

typedef __attribute__((ext_vector_type(8))) __bf16 bf16x8;
typedef __attribute__((ext_vector_type(4))) float  f32x4;
typedef _Float16 hf2 __attribute__((ext_vector_type(2)));

__device__ __forceinline__ unsigned pk2bf(float a, float b) {
    union { __bf16 h[2]; unsigned u; } r;
    r.h[0] = (__bf16)a; r.h[1] = (__bf16)b;   // v_cvt_pk_bf16_f32
    return r.u;
}
__device__ __forceinline__ unsigned pk2h(float a, float b) {
    __half2 h = __floats2half2_rn(a, b);
    return __builtin_bit_cast(unsigned, h);
}
__device__ __forceinline__ bf16x8 asbf(uint4 v) { return __builtin_bit_cast(bf16x8, v); }

// dtype probe + W1 -> per-lane bf16 MFMA B-fragment pack
__global__ void prep(const float* __restrict__ W1,
                     const unsigned* __restrict__ ei,
                     uint4* __restrict__ wpack,
                     int* __restrict__ flag, int do_pack) {
    const int t = threadIdx.x;
    if (t < 64) {
        unsigned v = ei[2 * t + 1];
        unsigned long long b = __ballot(v != 0u);
        if (t == 0) flag[0] = (b == 0ull) ? 1 : 0;
    }
    if (!do_pack) return;
    const int lane = t & 63;
    #pragma unroll
    for (int fi = 0; fi < 16; ++fi) {
        const int frag = (t >> 6) + fi * 4;
        const int kc = frag >> 3, jsg = frag & 7;
        const int k0 = kc * 32 + (lane >> 4) * 8;
        const int j  = jsg * 16 + (lane & 15);
        unsigned wv[4];
        #pragma unroll
        for (int p = 0; p < 4; ++p)
            wv[p] = pk2bf(W1[(k0 + 2 * p) * HID + j], W1[(k0 + 2 * p + 1) * HID + j]);
        wpack[frag * 64 + lane] = make_uint4(wv[0], wv[1], wv[2], wv[3]);
    }
}

// uv_gemm v4 (R12-proven) with fp16 output: quadrant-per-wave, W register-
// resident, zero LDS/barriers. UV row layout: byte jh*128 + l4*8 + jsg*2
// holds col j = jh*64 + jsg*16 + l4, as fp16.
__global__ __launch_bounds__(256)
void uv_gemm(const float* __restrict__ z,
             const uint4* __restrict__ wpack,
             char* __restrict__ ubf, char* __restrict__ vbf,
             int nwt)
{
    const int t = threadIdx.x, lane = t & 63, w = t >> 6;
    const int l4 = lane & 15, q = lane >> 4;
    const int jh = w & 1;
    char* obuf = (w >= 2) ? vbf : ubf;

    uint4 Bf[4][4];
    #pragma unroll
    for (int kc = 0; kc < 4; ++kc)
        #pragma unroll
        for (int jsg = 0; jsg < 4; ++jsg)
            Bf[kc][jsg] = wpack[((((w >> 1) * 4 + kc) * 8) + jh * 4 + jsg) * 64 + lane];

    for (int wt = blockIdx.x; wt < nwt; wt += gridDim.x) {
        #pragma unroll
        for (int kc = 0; kc < 4; ++kc)
            #pragma unroll
            for (int jsg = 0; jsg < 4; ++jsg)
                asm volatile("" : "+v"(Bf[kc][jsg].x), "+v"(Bf[kc][jsg].y),
                                  "+v"(Bf[kc][jsg].z), "+v"(Bf[kc][jsg].w));

        const int node0 = wt * 16;
        const float* zr = z + (long long)(node0 + l4) * IN_DIM + q * 8;

        f32x4 acc[4] = {};
        #pragma unroll
        for (int kc = 0; kc < 4; ++kc) {
            const float4 f0 = *reinterpret_cast<const float4*>(zr + kc * 32);
            const float4 f1 = *reinterpret_cast<const float4*>(zr + kc * 32 + 4);
            const bf16x8 a = asbf(make_uint4(pk2bf(f0.x, f0.y), pk2bf(f0.z, f0.w),
                                             pk2bf(f1.x, f1.y), pk2bf(f1.z, f1.w)));
            #pragma unroll
            for (int jsg = 0; jsg < 4; ++jsg)
                acc[jsg] = __builtin_amdgcn_mfma_f32_16x16x32_bf16(
                    a, asbf(Bf[kc][jsg]), acc[jsg], 0, 0, 0);
        }

        #pragma unroll
        for (int reg = 0; reg < 4; ++reg) {
            const int n = node0 + q * 4 + reg;
            *reinterpret_cast<uint2*>(obuf + (long long)n * 256 + jh * 128 + l4 * 8) =
                make_uint2(pk2h(acc[0][reg], acc[1][reg]),
                           pk2h(acc[2][reg], acc[3][reg]));
        }
    }
}

// Edge phase: streaming gather, packed-fp16 epilogue, 2 edges per 16-lane
// group for MLP. Lane g reads 16B at byte g*16 of each 256B row:
// dword pairs = (jsg0,jsg1)@la, (jsg2,jsg3)@la, (jsg0,jsg1)@lb, (jsg2,jsg3)@lb
// with la=2*(g&7), lb=la+1, jh=g>>3, col j = jh*64 + jsg*16 + l.
__global__ __launch_bounds__(256)
void lp_edge(const char* __restrict__ ubf, const char* __restrict__ vbf,
             const int* __restrict__ ei32,
             const float* __restrict__ b1, const float* __restrict__ W2,
             const float* __restrict__ b2, float* __restrict__ out,
             const int* __restrict__ flag, int E)
{
    const int t = threadIdx.x;
    const int g = t & 15;
    const int use64 = flag[0];
    const int jh = g >> 3, la = 2 * (g & 7), lb = la + 1;

    hf2 b1q[4], w2q[4];
    #pragma unroll
    for (int p = 0; p < 2; ++p) {          // p=0 -> (jsg0,jsg1), p=1 -> (jsg2,jsg3)
        b1q[p]     = hf2{(_Float16)b1[jh * 64 + (2 * p) * 16 + la],
                         (_Float16)b1[jh * 64 + (2 * p + 1) * 16 + la]};
        b1q[p + 2] = hf2{(_Float16)b1[jh * 64 + (2 * p) * 16 + lb],
                         (_Float16)b1[jh * 64 + (2 * p + 1) * 16 + lb]};
        w2q[p]     = hf2{(_Float16)W2[jh * 64 + (2 * p) * 16 + la],
                         (_Float16)W2[jh * 64 + (2 * p + 1) * 16 + la]};
        w2q[p + 2] = hf2{(_Float16)W2[jh * 64 + (2 * p) * 16 + lb],
                         (_Float16)W2[jh * 64 + (2 * p + 1) * 16 + lb]};
    }
    const hf2 zero2 = {(_Float16)0.f, (_Float16)0.f};
    const float b2v = b2[0];

#define STEP(ACC, U, V, K)                                                  \
    {                                                                       \
        const hf2 hu = __builtin_bit_cast(hf2, U);                          \
        const hf2 hv = __builtin_bit_cast(hf2, V);                          \
        const hf2 h  = __builtin_elementwise_max(hu + hv + b1q[K], zero2);  \
        ACC = __builtin_amdgcn_fdot2(h, w2q[K], ACC, false);                \
    }

    for (int e2 = blockIdx.x * 32 + ((t >> 4) << 1); e2 < E; e2 += gridDim.x * 32) {
        const int e3 = min(e2 + 1, E - 1);
        int s0 = ei32[(long long)e2 << use64];
        int d0 = ei32[(long long)(E + e2) << use64];
        int s1 = ei32[(long long)e3 << use64];
        int d1 = ei32[(long long)(E + e3) << use64];
        s0 = min(max(s0, 0), NN - 1); d0 = min(max(d0, 0), NN - 1);
        s1 = min(max(s1, 0), NN - 1); d1 = min(max(d1, 0), NN - 1);
        const uint4 uu0 = *reinterpret_cast<const uint4*>(ubf + (long long)s0 * 256 + g * 16);
        const uint4 vv0 = *reinterpret_cast<const uint4*>(vbf + (long long)d0 * 256 + g * 16);
        const uint4 uu1 = *reinterpret_cast<const uint4*>(ubf + (long long)s1 * 256 + g * 16);
        const uint4 vv1 = *reinterpret_cast<const uint4*>(vbf + (long long)d1 * 256 + g * 16);

        float a0 = 0.f, a1 = 0.f;
        STEP(a0, uu0.x, vv0.x, 0) STEP(a0, uu0.y, vv0.y, 1)
        STEP(a0, uu0.z, vv0.z, 2) STEP(a0, uu0.w, vv0.w, 3)
        STEP(a1, uu1.x, vv1.x, 0) STEP(a1, uu1.y, vv1.y, 1)
        STEP(a1, uu1.z, vv1.z, 2) STEP(a1, uu1.w, vv1.w, 3)

        #pragma unroll
        for (int o = 1; o <= 8; o <<= 1) {
            a0 += __shfl_xor(a0, o);
            a1 += __shfl_xor(a1, o);
        }
        // all 16 lanes hold both sums; lanes 0/1 store the two edges
        if (g < 2) {
            const int e = e2 + g;
            if (e < E && (g == 0 || e3 == e2 + 1))
                out[e] = 1.f / (1.f + expf(-((g ? a1 : a0) + b2v)));
        }
    }
#undef STEP
}

// ---------------- fallback (R5-proven fp32-gather kernel) ----------------
__global__ __launch_bounds__(256, 3)
void lp_main(const float* __restrict__ z,
             const int* __restrict__ ei32,
             const float* __restrict__ W1,
             const float* __restrict__ b1,
             const float* __restrict__ W2,
             const float* __restrict__ b2,
             float* __restrict__ out,
             const int* __restrict__ flag,
             const uint4* __restrict__ wpack,
             int use_ws, int E, int ntiles)
{
    __shared__ uint4 ldsA_[64 * 512 / 16];
    __shared__ float part[4][64];
    char* ldsc = (char*)ldsA_;

    const int t = threadIdx.x, lane = t & 63, w = t >> 6;
    const int use64 = flag[0];

    uint4 Bf[8][2];
    if (use_ws) {
        #pragma unroll
        for (int kc = 0; kc < 8; ++kc)
            #pragma unroll
            for (int js = 0; js < 2; ++js)
                Bf[kc][js] = wpack[(kc * 8 + (w * 2 + js)) * 64 + lane];
    } else {
        #pragma unroll
        for (int kc = 0; kc < 8; ++kc)
            #pragma unroll
            for (int js = 0; js < 2; ++js) {
                const int k0 = kc * 32 + (lane >> 4) * 8;
                const int j  = (w * 2 + js) * 16 + (lane & 15);
                unsigned wv[4];
                #pragma unroll
                for (int p = 0; p < 4; ++p)
                    wv[p] = pk2bf(W1[(k0 + 2 * p) * HID + j],
                                  W1[(k0 + 2 * p + 1) * HID + j]);
                Bf[kc][js] = make_uint4(wv[0], wv[1], wv[2], wv[3]);
            }
    }

    const int e_r = lane & 15, q = lane >> 4, m16 = q * 16;
    const float b1v0 = b1[w * 32 + e_r], b1v1 = b1[w * 32 + 16 + e_r];
    const float w2v0 = W2[w * 32 + e_r], w2v1 = W2[w * 32 + 16 + e_r];
    const float b2v  = b2[0];

    for (int tile = blockIdx.x; tile < ntiles; tile += gridDim.x) {
        const int e0 = tile * 64;
        #pragma unroll 8
        for (int i = 0; i < 16; ++i) {
            const int el = i * 4 + w;
            int e = e0 + el; if (e > E - 1) e = E - 1;
            const int word = (lane < 32) ? e : (E + e);
            int node = ei32[(long long)word << use64];
            node = min(max(node, 0), NN - 1);
            const float4 v = *reinterpret_cast<const float4*>(
                &z[node * IN_DIM + (lane & 31) * 4]);
            const int byte = el * 512 + ((lane * 8) ^ ((el & 7) << 4));
            *reinterpret_cast<uint2*>(ldsc + byte) =
                make_uint2(pk2bf(v.x, v.y), pk2bf(v.z, v.w));
        }
        __syncthreads();

        f32x4 acc[4][2] = {};
        #pragma unroll
        for (int kc = 0; kc < 8; ++kc) {
            #pragma unroll
            for (int es = 0; es < 4; ++es) {
                const int row  = es * 16 + e_r;
                const int byte = row * 512 + ((kc * 64 + m16) ^ ((row & 7) << 4));
                const bf16x8 a = *reinterpret_cast<const bf16x8*>(ldsc + byte);
                acc[es][0] = __builtin_amdgcn_mfma_f32_16x16x32_bf16(
                    a, asbf(Bf[kc][0]), acc[es][0], 0, 0, 0);
                acc[es][1] = __builtin_amdgcn_mfma_f32_16x16x32_bf16(
                    a, asbf(Bf[kc][1]), acc[es][1], 0, 0, 0);
            }
        }

        float v16[16];
        #pragma unroll
        for (int es = 0; es < 4; ++es)
            #pragma unroll
            for (int reg = 0; reg < 4; ++reg)
                v16[es * 4 + reg] = fmaxf(acc[es][0][reg] + b1v0, 0.f) * w2v0
                                  + fmaxf(acc[es][1][reg] + b1v1, 0.f) * w2v1;
        #pragma unroll
        for (int rnd = 0; rnd < 4; ++rnd) {
            const int o = 1 << rnd, hl = 8 >> rnd;
            #pragma unroll
            for (int i = 0; i < hl; ++i) {
                const float a = v16[i], b = v16[i + hl];
                const float s = (lane & o) ? a : b;
                const float r = __shfl_xor(s, o);
                v16[i] = ((lane & o) ? b : a) + r;
            }
        }
        {
            const int lx  = lane & 15;
            const int idx = ((lx & 1) << 3) | ((lx & 2) << 1) | ((lx & 4) >> 1) | ((lx & 8) >> 3);
            const int edge = (idx >> 2) * 16 + q * 4 + (idx & 3);
            part[w][edge] = v16[0];
        }
        __syncthreads();

        if (t < 64) {
            const int e = e0 + t;
            if (e < E) {
                const float s = part[0][t] + part[1][t] + part[2][t] + part[3][t] + b2v;
                out[e] = 1.f / (1.f + expf(-s));
            }
        }
    }
}

extern "C" void kernel_launch(void* const* d_in, const int* in_sizes, int n_in,
                              void* d_out, int out_size, void* d_ws, size_t ws_size,
                              hipStream_t stream) {
    const float* z  = (const float*)d_in[0];
    const void*  ei = d_in[1];
    const float* W1 = (const float*)d_in[2];
    const float* b1 = (const float*)d_in[3];
    const float* W2 = (const float*)d_in[4];
    const float* b2 = (const float*)d_in[5];
    float* out = (float*)d_out;
    int*   flag  = (int*)d_ws;
    uint4* wpack = (uint4*)((char*)d_ws + WPACK_OFF);
    char*  ubf   = (char*)d_ws + UBF_OFF;
    char*  vbf   = (char*)d_ws + VBF_OFF;

    const int E = in_sizes[1] / 2;
    const int use_ws = (ws_size >= (size_t)(WPACK_OFF + WPACK_BYTES)) ? 1 : 0;
    const int use_uv = (ws_size >= (size_t)(VBF_OFF + VBF_BYTES)) ? 1 : 0;

    hipLaunchKernelGGL(prep, dim3(1), dim3(256), 0, stream,
                       W1, (const unsigned*)ei, wpack, flag, use_ws);

    if (use_uv) {
        const int nwt = NN / 16;                           // 6250, exact
        hipLaunchKernelGGL(uv_gemm, dim3(1024), dim3(256), 0, stream,
                           z, wpack, ubf, vbf, nwt);
        hipLaunchKernelGGL(lp_edge, dim3(2048), dim3(256), 0, stream,
                           ubf, vbf, (const int*)ei, b1, W2, b2, out, flag, E);
    } else {
        const int ntiles = (E + 63) / 64;
        const int grid = (ntiles < 768) ? ntiles : 768;
        hipLaunchKernelGGL(lp_main, dim3(grid), dim3(256), 0, stream,
                           z, (const int*)ei, W1, b1, W2, b2, out, flag, wpack,
                           use_ws, E, ntiles);
    }
}

// Round 15
// 82.357 us; speedup vs baseline: 3.1934x; 1.4121x over previous
//
#include <hip/hip_runtime.h>
#include <hip/hip_fp16.h>
#include <math.h>

#define IN_DIM 128
#define HID    128
#define NN     100000
#define WPACK_BYTES (64 * 64 * 16)       // 64 frags x 64 lanes x 16B = 64 KB
#define WPACK_OFF   64
#define UBF_OFF     (WPACK_OFF + WPACK_BYTES + 192)   // 256-aligned
#define UBF_BYTES   (NN * HID)                        // 12.8 MB (fp8)
#define VBF_OFF     (UBF_OFF + UBF_BYTES)
#define VBF_BYTES   (NN * HID)                        // 12.8 MB (fp8)

typedef __attribute__((ext_vector_type(8))) __bf16 bf16x8;
typedef __attribute__((ext_vector_type(4))) float  f32x4;
typedef __attribute__((ext_vector_type(2))) float  f32x2;

__device__ __forceinline__ unsigned pk2bf(float a, float b) {
    union { __bf16 h[2]; unsigned u; } r;
    r.h[0] = (__bf16)a; r.h[1] = (__bf16)b;   // v_cvt_pk_bf16_f32
    return r.u;
}
__device__ __forceinline__ bf16x8 asbf(uint4 v) { return __builtin_bit_cast(bf16x8, v); }

// dtype probe + W1 -> per-lane bf16 MFMA B-fragment pack
__global__ void prep(const float* __restrict__ W1,
                     const unsigned* __restrict__ ei,
                     uint4* __restrict__ wpack,
                     int* __restrict__ flag, int do_pack) {
    const int t = threadIdx.x;
    if (t < 64) {
        unsigned v = ei[2 * t + 1];
        unsigned long long b = __ballot(v != 0u);
        if (t == 0) flag[0] = (b == 0ull) ? 1 : 0;
    }
    if (!do_pack) return;
    const int lane = t & 63;
    #pragma unroll
    for (int fi = 0; fi < 16; ++fi) {
        const int frag = (t >> 6) + fi * 4;
        const int kc = frag >> 3, jsg = frag & 7;
        const int k0 = kc * 32 + (lane >> 4) * 8;
        const int j  = jsg * 16 + (lane & 15);
        unsigned wv[4];
        #pragma unroll
        for (int p = 0; p < 4; ++p)
            wv[p] = pk2bf(W1[(k0 + 2 * p) * HID + j], W1[(k0 + 2 * p + 1) * HID + j]);
        wpack[frag * 64 + lane] = make_uint4(wv[0], wv[1], wv[2], wv[3]);
    }
}

// uv_gemm (R12-proven structure) with fp8 e4m3 output: quadrant-per-wave,
// W register-resident, zero LDS/barriers. UV row = 128B; byte
// jh*64 + l4*4 + jsg holds col j = jh*64 + jsg*16 + l4, as e4m3.
__global__ __launch_bounds__(256)
void uv_gemm(const float* __restrict__ z,
             const uint4* __restrict__ wpack,
             char* __restrict__ ubf, char* __restrict__ vbf,
             int nwt)
{
    const int t = threadIdx.x, lane = t & 63, w = t >> 6;
    const int l4 = lane & 15, q = lane >> 4;
    const int jh = w & 1;
    char* obuf = (w >= 2) ? vbf : ubf;

    uint4 Bf[4][4];
    #pragma unroll
    for (int kc = 0; kc < 4; ++kc)
        #pragma unroll
        for (int jsg = 0; jsg < 4; ++jsg)
            Bf[kc][jsg] = wpack[((((w >> 1) * 4 + kc) * 8) + jh * 4 + jsg) * 64 + lane];

    for (int wt = blockIdx.x; wt < nwt; wt += gridDim.x) {
        #pragma unroll
        for (int kc = 0; kc < 4; ++kc)
            #pragma unroll
            for (int jsg = 0; jsg < 4; ++jsg)
                asm volatile("" : "+v"(Bf[kc][jsg].x), "+v"(Bf[kc][jsg].y),
                                  "+v"(Bf[kc][jsg].z), "+v"(Bf[kc][jsg].w));

        const int node0 = wt * 16;
        const float* zr = z + (long long)(node0 + l4) * IN_DIM + q * 8;

        f32x4 acc[4] = {};
        #pragma unroll
        for (int kc = 0; kc < 4; ++kc) {
            const float4 f0 = *reinterpret_cast<const float4*>(zr + kc * 32);
            const float4 f1 = *reinterpret_cast<const float4*>(zr + kc * 32 + 4);
            const bf16x8 a = asbf(make_uint4(pk2bf(f0.x, f0.y), pk2bf(f0.z, f0.w),
                                             pk2bf(f1.x, f1.y), pk2bf(f1.z, f1.w)));
            #pragma unroll
            for (int jsg = 0; jsg < 4; ++jsg)
                acc[jsg] = __builtin_amdgcn_mfma_f32_16x16x32_bf16(
                    a, asbf(Bf[kc][jsg]), acc[jsg], 0, 0, 0);
        }

        // pack 4 jsg values -> 1 dword of e4m3; 16 lanes = 64B contiguous
        #pragma unroll
        for (int reg = 0; reg < 4; ++reg) {
            const int n = node0 + q * 4 + reg;
            int pk = __builtin_amdgcn_cvt_pk_fp8_f32(acc[0][reg], acc[1][reg], 0, false);
            pk = __builtin_amdgcn_cvt_pk_fp8_f32(acc[2][reg], acc[3][reg], pk, true);
            *reinterpret_cast<int*>(obuf + (long long)n * 128 + jh * 64 + l4 * 4) = pk;
        }
    }
}

// Edge phase: streaming fp8 gather. Lane g reads 8B at byte g*8 of each
// 128B row: dword.x = (l4=la, jsg0..3), dword.y = (l4=lb, jsg0..3),
// la = 2*(g&7), lb = la+1, jh = g>>3, col j = jh*64 + jsg*16 + l4.
__global__ __launch_bounds__(256)
void lp_edge(const char* __restrict__ ubf, const char* __restrict__ vbf,
             const int* __restrict__ ei32,
             const float* __restrict__ b1, const float* __restrict__ W2,
             const float* __restrict__ b2, float* __restrict__ out,
             const int* __restrict__ flag, int E)
{
    const int t = threadIdx.x;
    const int g = t & 15;
    const int use64 = flag[0];
    const int jh = g >> 3, la = 2 * (g & 7), lb = la + 1;

    // tables: [0]=(jsg0,jsg1)@la, [1]=(jsg2,jsg3)@la, [2],[3] same @lb
    f32x2 b1f[4], w2f[4];
    #pragma unroll
    for (int p = 0; p < 2; ++p) {
        const int l = p ? lb : la;
        b1f[2 * p]     = f32x2{b1[jh * 64 + l],      b1[jh * 64 + 16 + l]};
        b1f[2 * p + 1] = f32x2{b1[jh * 64 + 32 + l], b1[jh * 64 + 48 + l]};
        w2f[2 * p]     = f32x2{W2[jh * 64 + l],      W2[jh * 64 + 16 + l]};
        w2f[2 * p + 1] = f32x2{W2[jh * 64 + 32 + l], W2[jh * 64 + 48 + l]};
    }
    const f32x2 zf2 = {0.f, 0.f};
    const float b2v = b2[0];

// NOTE: macro locals use q0..q3 (NOT a0..) — R14 failed on the macro local
// shadowing the ACC argument (caller's a0) and binding ACC to a f32x2.
#define EDOT(ACC, UU, VV)                                                     \
    {                                                                         \
        f32x2 q0 = __builtin_amdgcn_cvt_pk_f32_fp8(UU.x, false)               \
                 + __builtin_amdgcn_cvt_pk_f32_fp8(VV.x, false) + b1f[0];     \
        f32x2 q1 = __builtin_amdgcn_cvt_pk_f32_fp8(UU.x, true)                \
                 + __builtin_amdgcn_cvt_pk_f32_fp8(VV.x, true) + b1f[1];      \
        f32x2 q2 = __builtin_amdgcn_cvt_pk_f32_fp8(UU.y, false)               \
                 + __builtin_amdgcn_cvt_pk_f32_fp8(VV.y, false) + b1f[2];     \
        f32x2 q3 = __builtin_amdgcn_cvt_pk_f32_fp8(UU.y, true)                \
                 + __builtin_amdgcn_cvt_pk_f32_fp8(VV.y, true) + b1f[3];      \
        q0 = __builtin_elementwise_max(q0, zf2);                              \
        q1 = __builtin_elementwise_max(q1, zf2);                              \
        q2 = __builtin_elementwise_max(q2, zf2);                              \
        q3 = __builtin_elementwise_max(q3, zf2);                              \
        ACC = fmaf(q0.x, w2f[0].x, fmaf(q0.y, w2f[0].y, ACC));                \
        ACC = fmaf(q1.x, w2f[1].x, fmaf(q1.y, w2f[1].y, ACC));                \
        ACC = fmaf(q2.x, w2f[2].x, fmaf(q2.y, w2f[2].y, ACC));                \
        ACC = fmaf(q3.x, w2f[3].x, fmaf(q3.y, w2f[3].y, ACC));                \
    }

    for (int e2 = blockIdx.x * 32 + ((t >> 4) << 1); e2 < E; e2 += gridDim.x * 32) {
        const int e3 = min(e2 + 1, E - 1);
        int s0 = ei32[(long long)e2 << use64];
        int d0 = ei32[(long long)(E + e2) << use64];
        int s1 = ei32[(long long)e3 << use64];
        int d1 = ei32[(long long)(E + e3) << use64];
        s0 = min(max(s0, 0), NN - 1); d0 = min(max(d0, 0), NN - 1);
        s1 = min(max(s1, 0), NN - 1); d1 = min(max(d1, 0), NN - 1);
        const uint2 uu0 = *reinterpret_cast<const uint2*>(ubf + (long long)s0 * 128 + g * 8);
        const uint2 vv0 = *reinterpret_cast<const uint2*>(vbf + (long long)d0 * 128 + g * 8);
        const uint2 uu1 = *reinterpret_cast<const uint2*>(ubf + (long long)s1 * 128 + g * 8);
        const uint2 vv1 = *reinterpret_cast<const uint2*>(vbf + (long long)d1 * 128 + g * 8);

        float sum0 = 0.f, sum1 = 0.f;
        EDOT(sum0, uu0, vv0)
        EDOT(sum1, uu1, vv1)

        #pragma unroll
        for (int o = 1; o <= 8; o <<= 1) {
            sum0 += __shfl_xor(sum0, o);
            sum1 += __shfl_xor(sum1, o);
        }
        if (g < 2) {
            const int e = e2 + g;
            if (e < E && (g == 0 || e3 == e2 + 1))
                out[e] = 1.f / (1.f + expf(-((g ? sum1 : sum0) + b2v)));
        }
    }
#undef EDOT
}

// ---------------- fallback (R5-proven fp32-gather kernel) ----------------
__global__ __launch_bounds__(256, 3)
void lp_main(const float* __restrict__ z,
             const int* __restrict__ ei32,
             const float* __restrict__ W1,
             const float* __restrict__ b1,
             const float* __restrict__ W2,
             const float* __restrict__ b2,
             float* __restrict__ out,
             const int* __restrict__ flag,
             const uint4* __restrict__ wpack,
             int use_ws, int E, int ntiles)
{
    __shared__ uint4 ldsA_[64 * 512 / 16];
    __shared__ float part[4][64];
    char* ldsc = (char*)ldsA_;

    const int t = threadIdx.x, lane = t & 63, w = t >> 6;
    const int use64 = flag[0];

    uint4 Bf[8][2];
    if (use_ws) {
        #pragma unroll
        for (int kc = 0; kc < 8; ++kc)
            #pragma unroll
            for (int js = 0; js < 2; ++js)
                Bf[kc][js] = wpack[(kc * 8 + (w * 2 + js)) * 64 + lane];
    } else {
        #pragma unroll
        for (int kc = 0; kc < 8; ++kc)
            #pragma unroll
            for (int js = 0; js < 2; ++js) {
                const int k0 = kc * 32 + (lane >> 4) * 8;
                const int j  = (w * 2 + js) * 16 + (lane & 15);
                unsigned wv[4];
                #pragma unroll
                for (int p = 0; p < 4; ++p)
                    wv[p] = pk2bf(W1[(k0 + 2 * p) * HID + j],
                                  W1[(k0 + 2 * p + 1) * HID + j]);
                Bf[kc][js] = make_uint4(wv[0], wv[1], wv[2], wv[3]);
            }
    }

    const int e_r = lane & 15, q = lane >> 4, m16 = q * 16;
    const float b1v0 = b1[w * 32 + e_r], b1v1 = b1[w * 32 + 16 + e_r];
    const float w2v0 = W2[w * 32 + e_r], w2v1 = W2[w * 32 + 16 + e_r];
    const float b2v  = b2[0];

    for (int tile = blockIdx.x; tile < ntiles; tile += gridDim.x) {
        const int e0 = tile * 64;
        #pragma unroll 8
        for (int i = 0; i < 16; ++i) {
            const int el = i * 4 + w;
            int e = e0 + el; if (e > E - 1) e = E - 1;
            const int word = (lane < 32) ? e : (E + e);
            int node = ei32[(long long)word << use64];
            node = min(max(node, 0), NN - 1);
            const float4 v = *reinterpret_cast<const float4*>(
                &z[node * IN_DIM + (lane & 31) * 4]);
            const int byte = el * 512 + ((lane * 8) ^ ((el & 7) << 4));
            *reinterpret_cast<uint2*>(ldsc + byte) =
                make_uint2(pk2bf(v.x, v.y), pk2bf(v.z, v.w));
        }
        __syncthreads();

        f32x4 acc[4][2] = {};
        #pragma unroll
        for (int kc = 0; kc < 8; ++kc) {
            #pragma unroll
            for (int es = 0; es < 4; ++es) {
                const int row  = es * 16 + e_r;
                const int byte = row * 512 + ((kc * 64 + m16) ^ ((row & 7) << 4));
                const bf16x8 a = *reinterpret_cast<const bf16x8*>(ldsc + byte);
                acc[es][0] = __builtin_amdgcn_mfma_f32_16x16x32_bf16(
                    a, asbf(Bf[kc][0]), acc[es][0], 0, 0, 0);
                acc[es][1] = __builtin_amdgcn_mfma_f32_16x16x32_bf16(
                    a, asbf(Bf[kc][1]), acc[es][1], 0, 0, 0);
            }
        }

        float v16[16];
        #pragma unroll
        for (int es = 0; es < 4; ++es)
            #pragma unroll
            for (int reg = 0; reg < 4; ++reg)
                v16[es * 4 + reg] = fmaxf(acc[es][0][reg] + b1v0, 0.f) * w2v0
                                  + fmaxf(acc[es][1][reg] + b1v1, 0.f) * w2v1;
        #pragma unroll
        for (int rnd = 0; rnd < 4; ++rnd) {
            const int o = 1 << rnd, hl = 8 >> rnd;
            #pragma unroll
            for (int i = 0; i < hl; ++i) {
                const float a = v16[i], b = v16[i + hl];
                const float s = (lane & o) ? a : b;
                const float r = __shfl_xor(s, o);
                v16[i] = ((lane & o) ? b : a) + r;
            }
        }
        {
            const int lx  = lane & 15;
            const int idx = ((lx & 1) << 3) | ((lx & 2) << 1) | ((lx & 4) >> 1) | ((lx & 8) >> 3);
            const int edge = (idx >> 2) * 16 + q * 4 + (idx & 3);
            part[w][edge] = v16[0];
        }
        __syncthreads();

        if (t < 64) {
            const int e = e0 + t;
            if (e < E) {
                const float s = part[0][t] + part[1][t] + part[2][t] + part[3][t] + b2v;
                out[e] = 1.f / (1.f + expf(-s));
            }
        }
    }
}

extern "C" void kernel_launch(void* const* d_in, const int* in_sizes, int n_in,
                              void* d_out, int out_size, void* d_ws, size_t ws_size,
                              hipStream_t stream) {
    const float* z  = (const float*)d_in[0];
    const void*  ei = d_in[1];
    const float* W1 = (const float*)d_in[2];
    const float* b1 = (const float*)d_in[3];
    const float* W2 = (const float*)d_in[4];
    const float* b2 = (const float*)d_in[5];
    float* out = (float*)d_out;
    int*   flag  = (int*)d_ws;
    uint4* wpack = (uint4*)((char*)d_ws + WPACK_OFF);
    char*  ubf   = (char*)d_ws + UBF_OFF;
    char*  vbf   = (char*)d_ws + VBF_OFF;

    const int E = in_sizes[1] / 2;
    const int use_ws = (ws_size >= (size_t)(WPACK_OFF + WPACK_BYTES)) ? 1 : 0;
    const int use_uv = (ws_size >= (size_t)(VBF_OFF + VBF_BYTES)) ? 1 : 0;

    hipLaunchKernelGGL(prep, dim3(1), dim3(256), 0, stream,
                       W1, (const unsigned*)ei, wpack, flag, use_ws);

    if (use_uv) {
        const int nwt = NN / 16;                           // 6250, exact
        hipLaunchKernelGGL(uv_gemm, dim3(1024), dim3(256), 0, stream,
                           z, wpack, ubf, vbf, nwt);
        hipLaunchKernelGGL(lp_edge, dim3(2048), dim3(256), 0, stream,
                           ubf, vbf, (const int*)ei, b1, W2, b2, out, flag, E);
    } else {
        const int ntiles = (E + 63) / 64;
        const int grid = (ntiles < 768) ? ntiles : 768;
        hipLaunchKernelGGL(lp_main, dim3(grid), dim3(256), 0, stream,
                           z, (const int*)ei, W1, b1, W2, b2, out, flag, wpack,
                           use_ws, E, ntiles);
    }
}

// Round 17
// 79.752 us; speedup vs baseline: 3.2977x; 1.0327x over previous
//
#include <hip/hip_runtime.h>
#include <hip/hip_fp16.h>
#include <math.h>

#define IN_DIM 128
#define HID    128
#define NN     100000
#define WPACK_BYTES (64 * 64 * 16)       // 64 frags x 64 lanes x 16B = 64 KB
#define WPACK_OFF   64
#define UBF_OFF     (WPACK_OFF + WPACK_BYTES + 192)   // 256-aligned
#define UBF_BYTES   (NN * HID)                        // 12.8 MB (fp8)
#define VBF_OFF     (UBF_OFF + UBF_BYTES)
#define VBF_BYTES   (NN * HID)                        // 12.8 MB (fp8)

typedef __attribute__((ext_vector_type(8))) __bf16 bf16x8;
typedef __attribute__((ext_vector_type(4))) float  f32x4;
typedef __attribute__((ext_vector_type(2))) float  f32x2;

__device__ __forceinline__ unsigned pk2bf(float a, float b) {
    union { __bf16 h[2]; unsigned u; } r;
    r.h[0] = (__bf16)a; r.h[1] = (__bf16)b;   // v_cvt_pk_bf16_f32
    return r.u;
}
__device__ __forceinline__ bf16x8 asbf(uint4 v) { return __builtin_bit_cast(bf16x8, v); }

// dtype probe (block 0) + W1 -> bf16 B-fragment pack, 16 blocks x 4 frags.
__global__ void prep(const float* __restrict__ W1,
                     const unsigned* __restrict__ ei,
                     uint4* __restrict__ wpack,
                     int* __restrict__ flag, int do_pack) {
    const int t = threadIdx.x;
    if (blockIdx.x == 0 && t < 64) {
        unsigned v = ei[2 * t + 1];
        unsigned long long b = __ballot(v != 0u);
        if (t == 0) flag[0] = (b == 0ull) ? 1 : 0;
    }
    if (!do_pack) return;
    const int lane = t & 63;
    const int frag = (t >> 6) + blockIdx.x * 4;      // grid 16 -> frags 0..63
    const int kc = frag >> 3, jsg = frag & 7;
    const int k0 = kc * 32 + (lane >> 4) * 8;
    const int j  = jsg * 16 + (lane & 15);
    unsigned wv[4];
    #pragma unroll
    for (int p = 0; p < 4; ++p)
        wv[p] = pk2bf(W1[(k0 + 2 * p) * HID + j], W1[(k0 + 2 * p + 1) * HID + j]);
    wpack[frag * 64 + lane] = make_uint4(wv[0], wv[1], wv[2], wv[3]);
}

// uv_gemm v6: quadrant-per-wave — ALL 4 WAVES OF A BLOCK SHARE ONE TILE
// (R16's per-wave tiles left 3/4 of each row unwritten). Each block does
// exactly 2 tiles: wt = blockIdx.x + i*half_nwt, grid = half_nwt = 3125 ->
// perfect balance, ~12 blocks/CU. Bf (16KB/wave quadrant) loaded once.
// UV row = 128B fp8; byte jh*64 + l4*4 + jsg = col j = jh*64 + jsg*16 + l4.
__global__ __launch_bounds__(256)
void uv_gemm(const float* __restrict__ z,
             const uint4* __restrict__ wpack,
             char* __restrict__ ubf, char* __restrict__ vbf,
             int half_nwt)
{
    const int t = threadIdx.x, lane = t & 63, w = t >> 6;
    const int l4 = lane & 15, q = lane >> 4;
    const int jh = w & 1;
    char* obuf = (w >= 2) ? vbf : ubf;

    uint4 Bf[4][4];
    #pragma unroll
    for (int kc = 0; kc < 4; ++kc)
        #pragma unroll
        for (int jsg = 0; jsg < 4; ++jsg)
            Bf[kc][jsg] = wpack[((((w >> 1) * 4 + kc) * 8) + jh * 4 + jsg) * 64 + lane];

    #pragma unroll
    for (int i = 0; i < 2; ++i) {
        // keep Bf live across both tiles (R12/R15-proven pin; VGPR ~80, no spill)
        #pragma unroll
        for (int kc = 0; kc < 4; ++kc)
            #pragma unroll
            for (int jsg = 0; jsg < 4; ++jsg)
                asm volatile("" : "+v"(Bf[kc][jsg].x), "+v"(Bf[kc][jsg].y),
                                  "+v"(Bf[kc][jsg].z), "+v"(Bf[kc][jsg].w));

        const int wt = blockIdx.x + i * half_nwt;     // 2*half_nwt == nwt exactly
        const int node0 = wt * 16;
        const float* zr = z + (long long)(node0 + l4) * IN_DIM + q * 8;

        f32x4 acc[4] = {};
        #pragma unroll
        for (int kc = 0; kc < 4; ++kc) {
            const float4 f0 = *reinterpret_cast<const float4*>(zr + kc * 32);
            const float4 f1 = *reinterpret_cast<const float4*>(zr + kc * 32 + 4);
            const bf16x8 a = asbf(make_uint4(pk2bf(f0.x, f0.y), pk2bf(f0.z, f0.w),
                                             pk2bf(f1.x, f1.y), pk2bf(f1.z, f1.w)));
            #pragma unroll
            for (int jsg = 0; jsg < 4; ++jsg)
                acc[jsg] = __builtin_amdgcn_mfma_f32_16x16x32_bf16(
                    a, asbf(Bf[kc][jsg]), acc[jsg], 0, 0, 0);
        }

        // pack 4 jsg values -> 1 dword of e4m3; 16 lanes = 64B contiguous
        #pragma unroll
        for (int reg = 0; reg < 4; ++reg) {
            const int n = node0 + q * 4 + reg;
            int pk = __builtin_amdgcn_cvt_pk_fp8_f32(acc[0][reg], acc[1][reg], 0, false);
            pk = __builtin_amdgcn_cvt_pk_fp8_f32(acc[2][reg], acc[3][reg], pk, true);
            *reinterpret_cast<int*>(obuf + (long long)n * 128 + jh * 64 + l4 * 4) = pk;
        }
    }
}

// Edge phase (R15-proven): streaming fp8 gather. Lane g reads 8B at byte g*8
// of each 128B row: dword.x = (l4=la, jsg0..3), dword.y = (l4=lb, jsg0..3),
// la = 2*(g&7), lb = la+1, jh = g>>3, col j = jh*64 + jsg*16 + l4.
__global__ __launch_bounds__(256)
void lp_edge(const char* __restrict__ ubf, const char* __restrict__ vbf,
             const int* __restrict__ ei32,
             const float* __restrict__ b1, const float* __restrict__ W2,
             const float* __restrict__ b2, float* __restrict__ out,
             const int* __restrict__ flag, int E)
{
    const int t = threadIdx.x;
    const int g = t & 15;
    const int use64 = flag[0];
    const int jh = g >> 3, la = 2 * (g & 7), lb = la + 1;

    f32x2 b1f[4], w2f[4];
    #pragma unroll
    for (int p = 0; p < 2; ++p) {
        const int l = p ? lb : la;
        b1f[2 * p]     = f32x2{b1[jh * 64 + l],      b1[jh * 64 + 16 + l]};
        b1f[2 * p + 1] = f32x2{b1[jh * 64 + 32 + l], b1[jh * 64 + 48 + l]};
        w2f[2 * p]     = f32x2{W2[jh * 64 + l],      W2[jh * 64 + 16 + l]};
        w2f[2 * p + 1] = f32x2{W2[jh * 64 + 32 + l], W2[jh * 64 + 48 + l]};
    }
    const f32x2 zf2 = {0.f, 0.f};
    const float b2v = b2[0];

// macro locals q0..q3 — must not collide with caller names (R14 lesson)
#define EDOT(ACC, UU, VV)                                                     \
    {                                                                         \
        f32x2 q0 = __builtin_amdgcn_cvt_pk_f32_fp8(UU.x, false)               \
                 + __builtin_amdgcn_cvt_pk_f32_fp8(VV.x, false) + b1f[0];     \
        f32x2 q1 = __builtin_amdgcn_cvt_pk_f32_fp8(UU.x, true)                \
                 + __builtin_amdgcn_cvt_pk_f32_fp8(VV.x, true) + b1f[1];      \
        f32x2 q2 = __builtin_amdgcn_cvt_pk_f32_fp8(UU.y, false)               \
                 + __builtin_amdgcn_cvt_pk_f32_fp8(VV.y, false) + b1f[2];     \
        f32x2 q3 = __builtin_amdgcn_cvt_pk_f32_fp8(UU.y, true)                \
                 + __builtin_amdgcn_cvt_pk_f32_fp8(VV.y, true) + b1f[3];      \
        q0 = __builtin_elementwise_max(q0, zf2);                              \
        q1 = __builtin_elementwise_max(q1, zf2);                              \
        q2 = __builtin_elementwise_max(q2, zf2);                              \
        q3 = __builtin_elementwise_max(q3, zf2);                              \
        ACC = fmaf(q0.x, w2f[0].x, fmaf(q0.y, w2f[0].y, ACC));                \
        ACC = fmaf(q1.x, w2f[1].x, fmaf(q1.y, w2f[1].y, ACC));                \
        ACC = fmaf(q2.x, w2f[2].x, fmaf(q2.y, w2f[2].y, ACC));                \
        ACC = fmaf(q3.x, w2f[3].x, fmaf(q3.y, w2f[3].y, ACC));                \
    }

    for (int e2 = blockIdx.x * 32 + ((t >> 4) << 1); e2 < E; e2 += gridDim.x * 32) {
        const int e3 = min(e2 + 1, E - 1);
        int s0 = ei32[(long long)e2 << use64];
        int d0 = ei32[(long long)(E + e2) << use64];
        int s1 = ei32[(long long)e3 << use64];
        int d1 = ei32[(long long)(E + e3) << use64];
        s0 = min(max(s0, 0), NN - 1); d0 = min(max(d0, 0), NN - 1);
        s1 = min(max(s1, 0), NN - 1); d1 = min(max(d1, 0), NN - 1);
        const uint2 uu0 = *reinterpret_cast<const uint2*>(ubf + (long long)s0 * 128 + g * 8);
        const uint2 vv0 = *reinterpret_cast<const uint2*>(vbf + (long long)d0 * 128 + g * 8);
        const uint2 uu1 = *reinterpret_cast<const uint2*>(ubf + (long long)s1 * 128 + g * 8);
        const uint2 vv1 = *reinterpret_cast<const uint2*>(vbf + (long long)d1 * 128 + g * 8);

        float sum0 = 0.f, sum1 = 0.f;
        EDOT(sum0, uu0, vv0)
        EDOT(sum1, uu1, vv1)

        #pragma unroll
        for (int o = 1; o <= 8; o <<= 1) {
            sum0 += __shfl_xor(sum0, o);
            sum1 += __shfl_xor(sum1, o);
        }
        if (g < 2) {
            const int e = e2 + g;
            if (e < E && (g == 0 || e3 == e2 + 1))
                out[e] = 1.f / (1.f + expf(-((g ? sum1 : sum0) + b2v)));
        }
    }
#undef EDOT
}

// ---------------- fallback (R5-proven fp32-gather kernel) ----------------
__global__ __launch_bounds__(256, 3)
void lp_main(const float* __restrict__ z,
             const int* __restrict__ ei32,
             const float* __restrict__ W1,
             const float* __restrict__ b1,
             const float* __restrict__ W2,
             const float* __restrict__ b2,
             float* __restrict__ out,
             const int* __restrict__ flag,
             const uint4* __restrict__ wpack,
             int use_ws, int E, int ntiles)
{
    __shared__ uint4 ldsA_[64 * 512 / 16];
    __shared__ float part[4][64];
    char* ldsc = (char*)ldsA_;

    const int t = threadIdx.x, lane = t & 63, w = t >> 6;
    const int use64 = flag[0];

    uint4 Bf[8][2];
    if (use_ws) {
        #pragma unroll
        for (int kc = 0; kc < 8; ++kc)
            #pragma unroll
            for (int js = 0; js < 2; ++js)
                Bf[kc][js] = wpack[(kc * 8 + (w * 2 + js)) * 64 + lane];
    } else {
        #pragma unroll
        for (int kc = 0; kc < 8; ++kc)
            #pragma unroll
            for (int js = 0; js < 2; ++js) {
                const int k0 = kc * 32 + (lane >> 4) * 8;
                const int j  = (w * 2 + js) * 16 + (lane & 15);
                unsigned wv[4];
                #pragma unroll
                for (int p = 0; p < 4; ++p)
                    wv[p] = pk2bf(W1[(k0 + 2 * p) * HID + j],
                                  W1[(k0 + 2 * p + 1) * HID + j]);
                Bf[kc][js] = make_uint4(wv[0], wv[1], wv[2], wv[3]);
            }
    }

    const int e_r = lane & 15, q = lane >> 4, m16 = q * 16;
    const float b1v0 = b1[w * 32 + e_r], b1v1 = b1[w * 32 + 16 + e_r];
    const float w2v0 = W2[w * 32 + e_r], w2v1 = W2[w * 32 + 16 + e_r];
    const float b2v  = b2[0];

    for (int tile = blockIdx.x; tile < ntiles; tile += gridDim.x) {
        const int e0 = tile * 64;
        #pragma unroll 8
        for (int i = 0; i < 16; ++i) {
            const int el = i * 4 + w;
            int e = e0 + el; if (e > E - 1) e = E - 1;
            const int word = (lane < 32) ? e : (E + e);
            int node = ei32[(long long)word << use64];
            node = min(max(node, 0), NN - 1);
            const float4 v = *reinterpret_cast<const float4*>(
                &z[node * IN_DIM + (lane & 31) * 4]);
            const int byte = el * 512 + ((lane * 8) ^ ((el & 7) << 4));
            *reinterpret_cast<uint2*>(ldsc + byte) =
                make_uint2(pk2bf(v.x, v.y), pk2bf(v.z, v.w));
        }
        __syncthreads();

        f32x4 acc[4][2] = {};
        #pragma unroll
        for (int kc = 0; kc < 8; ++kc) {
            #pragma unroll
            for (int es = 0; es < 4; ++es) {
                const int row  = es * 16 + e_r;
                const int byte = row * 512 + ((kc * 64 + m16) ^ ((row & 7) << 4));
                const bf16x8 a = *reinterpret_cast<const bf16x8*>(ldsc + byte);
                acc[es][0] = __builtin_amdgcn_mfma_f32_16x16x32_bf16(
                    a, asbf(Bf[kc][0]), acc[es][0], 0, 0, 0);
                acc[es][1] = __builtin_amdgcn_mfma_f32_16x16x32_bf16(
                    a, asbf(Bf[kc][1]), acc[es][1], 0, 0, 0);
            }
        }

        float v16[16];
        #pragma unroll
        for (int es = 0; es < 4; ++es)
            #pragma unroll
            for (int reg = 0; reg < 4; ++reg)
                v16[es * 4 + reg] = fmaxf(acc[es][0][reg] + b1v0, 0.f) * w2v0
                                  + fmaxf(acc[es][1][reg] + b1v1, 0.f) * w2v1;
        #pragma unroll
        for (int rnd = 0; rnd < 4; ++rnd) {
            const int o = 1 << rnd, hl = 8 >> rnd;
            #pragma unroll
            for (int i = 0; i < hl; ++i) {
                const float a = v16[i], b = v16[i + hl];
                const float s = (lane & o) ? a : b;
                const float r = __shfl_xor(s, o);
                v16[i] = ((lane & o) ? b : a) + r;
            }
        }
        {
            const int lx  = lane & 15;
            const int idx = ((lx & 1) << 3) | ((lx & 2) << 1) | ((lx & 4) >> 1) | ((lx & 8) >> 3);
            const int edge = (idx >> 2) * 16 + q * 4 + (idx & 3);
            part[w][edge] = v16[0];
        }
        __syncthreads();

        if (t < 64) {
            const int e = e0 + t;
            if (e < E) {
                const float s = part[0][t] + part[1][t] + part[2][t] + part[3][t] + b2v;
                out[e] = 1.f / (1.f + expf(-s));
            }
        }
    }
}

extern "C" void kernel_launch(void* const* d_in, const int* in_sizes, int n_in,
                              void* d_out, int out_size, void* d_ws, size_t ws_size,
                              hipStream_t stream) {
    const float* z  = (const float*)d_in[0];
    const void*  ei = d_in[1];
    const float* W1 = (const float*)d_in[2];
    const float* b1 = (const float*)d_in[3];
    const float* W2 = (const float*)d_in[4];
    const float* b2 = (const float*)d_in[5];
    float* out = (float*)d_out;
    int*   flag  = (int*)d_ws;
    uint4* wpack = (uint4*)((char*)d_ws + WPACK_OFF);
    char*  ubf   = (char*)d_ws + UBF_OFF;
    char*  vbf   = (char*)d_ws + VBF_OFF;

    const int E = in_sizes[1] / 2;
    const int use_ws = (ws_size >= (size_t)(WPACK_OFF + WPACK_BYTES)) ? 1 : 0;
    const int use_uv = (ws_size >= (size_t)(VBF_OFF + VBF_BYTES)) ? 1 : 0;

    hipLaunchKernelGGL(prep, dim3(16), dim3(256), 0, stream,
                       W1, (const unsigned*)ei, wpack, flag, use_ws);

    if (use_uv) {
        const int half_nwt = NN / 32;                      // 3125: 2 tiles/block
        hipLaunchKernelGGL(uv_gemm, dim3(half_nwt), dim3(256), 0, stream,
                           z, wpack, ubf, vbf, half_nwt);
        hipLaunchKernelGGL(lp_edge, dim3(2048), dim3(256), 0, stream,
                           ubf, vbf, (const int*)ei, b1, W2, b2, out, flag, E);
    } else {
        const int ntiles = (E + 63) / 64;
        const int grid = (ntiles < 768) ? ntiles : 768;
        hipLaunchKernelGGL(lp_main, dim3(grid), dim3(256), 0, stream,
                           z, (const int*)ei, W1, b1, W2, b2, out, flag, wpack,
                           use_ws, E, ntiles);
    }
}